// Round 9
// baseline (450.189 us; speedup 1.0000x reference)
//
#include <hip/hip_runtime.h>

// OverISS-T  (input (2,4,512,1000) complex, 5 iterations)
// Multi-kernel, stream-ordered. Y state lives in d_out (Yr | Yi planes, final
// output layout). W/H are dead state w.r.t. Y — skipped.
//
// Round 9 (base = R8):
//  - iter_c: FOUR waves per block (256 thr, 4 frame-slots/thread)
//    -> 16 waves/CU = 4 waves/SIMD (was 2). One barrier per stage kept via
//    parity-double-buffered float4 combine buffer; cross-wave combine is
//    12 broadcast ds_read_b128 + 9 float4 adds.
//  - everything else (DPP wave reduction, register tap-windows, mag-plane
//    sumf pipeline, fast rcp/rsqrt) carried over from R8.

constexpr int NCH = 4;
constexpr int NFQ = 512;
constexpr int NFR = 1000;
constexpr int NIT = 5;
constexpr float EPSV  = 1e-3f;
constexpr float INVNF = 1.0f / 1000.0f;
constexpr float INVFN = 1.0f / (512.0f * 1000.0f);
constexpr size_t PLANE = 4096000;             // 2*4*512*1000
constexpr size_t CSTRIDE = (size_t)NFQ * NFR; // 512000

__device__ __forceinline__ float fast_rcp(float x) { return __builtin_amdgcn_rcpf(x); }
__device__ __forceinline__ float fast_rsq(float x) { return __builtin_amdgcn_rsqf(x); }

template <int CTRL>
__device__ __forceinline__ float dpp_add(float x) {
  return x + __int_as_float(__builtin_amdgcn_update_dpp(
      0, __float_as_int(x), CTRL, 0xF, 0xF, true));
}
__device__ __forceinline__ float wave_red(float x) {
  x = dpp_add<0xB1>(x);    // quad_perm [1,0,3,2]
  x = dpp_add<0x4E>(x);    // quad_perm [2,3,0,1]
  x = dpp_add<0x141>(x);   // row_half_mirror
  x = dpp_add<0x140>(x);   // row_mirror
  x = dpp_add<0x142>(x);   // row_bcast15
  x = dpp_add<0x143>(x);   // row_bcast31
  return __int_as_float(__builtin_amdgcn_readlane(__float_as_int(x), 63));
}
__device__ __forceinline__ float4 f4add(float4 a, float4 b) {
  return make_float4(a.x + b.x, a.y + b.y, a.z + b.z, a.w + b.w);
}

// ---- Y0 = 0.999*X[c] + 0.001*sum_d X[d];  optional |Y0|^2 plane ----
__global__ __launch_bounds__(256, 4)
void init_y(const float* __restrict__ Xr, const float* __restrict__ Xi,
            float* __restrict__ Y, float* __restrict__ mag)
{
  const int bf = blockIdx.x, b = bf >> 9, f = bf & 511;
  const size_t base = ((size_t)b * NCH * NFQ + f) * NFR;
  const int tid = threadIdx.x;
  if (tid < 250) {
    const int nq = 4 * tid;
    float4 xr[4], xi[4];
    #pragma unroll
    for (int c = 0; c < 4; ++c) {
      xr[c] = *(const float4*)(Xr + base + (size_t)c * CSTRIDE + nq);
      xi[c] = *(const float4*)(Xi + base + (size_t)c * CSTRIDE + nq);
    }
    float4 sr, si;
    sr.x = xr[0].x+xr[1].x+xr[2].x+xr[3].x;  si.x = xi[0].x+xi[1].x+xi[2].x+xi[3].x;
    sr.y = xr[0].y+xr[1].y+xr[2].y+xr[3].y;  si.y = xi[0].y+xi[1].y+xi[2].y+xi[3].y;
    sr.z = xr[0].z+xr[1].z+xr[2].z+xr[3].z;  si.z = xi[0].z+xi[1].z+xi[2].z+xi[3].z;
    sr.w = xr[0].w+xr[1].w+xr[2].w+xr[3].w;  si.w = xi[0].w+xi[1].w+xi[2].w+xi[3].w;
    #pragma unroll
    for (int c = 0; c < 4; ++c) {
      float4 yr, yi;
      yr.x = 0.999f*xr[c].x + 0.001f*sr.x;  yi.x = 0.999f*xi[c].x + 0.001f*si.x;
      yr.y = 0.999f*xr[c].y + 0.001f*sr.y;  yi.y = 0.999f*xi[c].y + 0.001f*si.y;
      yr.z = 0.999f*xr[c].z + 0.001f*sr.z;  yi.z = 0.999f*xi[c].z + 0.001f*si.z;
      yr.w = 0.999f*xr[c].w + 0.001f*sr.w;  yi.w = 0.999f*xi[c].w + 0.001f*si.w;
      *(float4*)(Y + base + (size_t)c * CSTRIDE + nq)         = yr;
      *(float4*)(Y + base + (size_t)c * CSTRIDE + nq + PLANE) = yi;
      if (mag) {
        float4 m;
        m.x = yr.x*yr.x + yi.x*yi.x;  m.y = yr.y*yr.y + yi.y*yi.y;
        m.z = yr.z*yr.z + yi.z*yi.z;  m.w = yr.w*yr.w + yi.w*yi.w;
        *(float4*)(mag + base + (size_t)c * CSTRIDE + nq) = m;
      }
    }
  }
}

// ---- mag reduction over f, stage 1: 32-f chunks (128 blocks) ----
__global__ __launch_bounds__(256, 4)
void partial_mag(const float* __restrict__ mag, float* __restrict__ part2)
{
  const int id = blockIdx.x;                  // b | c | k
  const int k = id & 15, c = (id >> 4) & 3, b = id >> 6;
  const int tid = threadIdx.x;
  if (tid < 250) {
    const int nq = 4 * tid;
    const float* base = mag + ((size_t)((b*4+c)*NFQ + k*32)) * NFR + nq;
    float4 acc = make_float4(0.f, 0.f, 0.f, 0.f);
    for (int ff = 0; ff < 32; ++ff) {
      const float4 v = *(const float4*)(base + (size_t)ff * NFR);
      acc.x += v.x; acc.y += v.y; acc.z += v.z; acc.w += v.w;
    }
    *(float4*)(part2 + ((size_t)((b*4+c)*16 + k)) * NFR + nq) = acc;
  }
}

// ---- mag reduction stage 2 ----
__global__ __launch_bounds__(256, 4)
void finish_mag(const float* __restrict__ part2, float* __restrict__ sumf)
{
  const int t = blockIdx.x * 256 + threadIdx.x;   // 8 blocks, 2000 quads
  if (t < 2000) {
    const int b = t / 1000, r = t - 1000 * b;
    const int c = r / 250,  qn = r - 250 * c;
    const float* base = part2 + ((size_t)((b*4+c)*16)) * NFR + 4*qn;
    float4 acc = make_float4(0.f, 0.f, 0.f, 0.f);
    #pragma unroll
    for (int k = 0; k < 16; ++k) {
      const float4 v = *(const float4*)(base + (size_t)k * NFR);
      acc.x += v.x; acc.y += v.y; acc.z += v.z; acc.w += v.w;
    }
    *(float4*)(sumf + (size_t)b*4000 + c*1000 + 4*qn) = acc;
  }
}

// ---- legacy sumf path (reads Y) — fallback when ws is small ----
__global__ __launch_bounds__(256, 4)
void partial_sumf(const float* __restrict__ Y, float* __restrict__ part)
{
  const int id = blockIdx.x;                 // b | c | q
  const int q = id & 31, c = (id >> 5) & 3, b = id >> 7;
  const size_t base = (size_t)(b * NCH + c) * CSTRIDE + (size_t)q * 16 * NFR;
  float acc[4] = {0.f, 0.f, 0.f, 0.f};
  for (int ff = 0; ff < 16; ++ff) {
    #pragma unroll
    for (int k = 0; k < 4; ++k) {
      const int n = threadIdx.x + 256 * k;
      if (n < NFR) {
        const float r = Y[base + (size_t)ff * NFR + n];
        const float i = Y[base + (size_t)ff * NFR + n + PLANE];
        acc[k] = fmaf(r, r, acc[k]);
        acc[k] = fmaf(i, i, acc[k]);
      }
    }
  }
  #pragma unroll
  for (int k = 0; k < 4; ++k) {
    const int n = threadIdx.x + 256 * k;
    if (n < NFR) part[((size_t)(b * NCH + c) * 32 + q) * NFR + n] = acc[k];
  }
}
__global__ __launch_bounds__(256, 4)
void finish_sumf(const float* __restrict__ part, float* __restrict__ sumf)
{
  const int o = blockIdx.x * 256 + threadIdx.x;
  if (o < 8000) {
    const int b = o / 4000;
    const int rem = o - b * 4000;
    const int c = rem / 1000;
    const int n = rem - c * 1000;
    const float* p = part + ((size_t)(b * NCH + c) * 32) * NFR + n;
    float s = 0.f;
    for (int q = 0; q < 32; ++q) s += p[(size_t)q * NFR];
    sumf[o] = s;
  }
}

// ---- stage C: one full iteration for one (b,f) slice — FOUR waves ----
// wave wid owns slots s=0..3: frame n = 256*wid + 64*s + lane
__global__ __launch_bounds__(256, 4)
void iter_c(const float* __restrict__ Xr, const float* __restrict__ Xi,
            float* __restrict__ Y, const float* __restrict__ sumf,
            float* __restrict__ mag)
{
  __shared__ float  xre[NCH][NFR];
  __shared__ float  xim[NCH][NFR];
  __shared__ float4 redv[2][4][3];   // [parity][wave][12 floats]
  __shared__ float4 gredv[4];        // per-wave g partials

  const int tid  = threadIdx.x;
  const int lane = tid & 63;
  const int wid  = tid >> 6;                // 0..3
  const int bf   = blockIdx.x, b = bf >> 9, f = bf & 511;
  const size_t base = ((size_t)b * NCH * NFQ + f) * NFR;
  const int nb = 256 * wid + lane;          // frame of slot 0

  // ---- stage X into LDS (float4 both sides) ----
  for (int j = tid; j < NCH * 250; j += 256) {
    const int c = j / 250, q = j - c * 250;
    *(float4*)(&xre[c][4*q]) = *(const float4*)(Xr + base + (size_t)c*CSTRIDE + 4*q);
    *(float4*)(&xim[c][4*q]) = *(const float4*)(Xi + base + (size_t)c*CSTRIDE + 4*q);
  }

  // ---- sumf -> g (cross-wave via gredv), invgs, weights w ----
  float w[4][4], invgs[4];
  {
    float sfr[4][4];
    const float* sfb = sumf + b * 4000;
    #pragma unroll
    for (int s = 0; s < 4; ++s) {
      const int na = min(nb + 64*s, 999);
      #pragma unroll
      for (int c = 0; c < 4; ++c) sfr[s][c] = sfb[c*1000 + na];
    }
    float gp[4] = {0.f, 0.f, 0.f, 0.f};
    #pragma unroll
    for (int s = 0; s < 4; ++s) {
      const bool valid = (nb + 64*s) < NFR;
      #pragma unroll
      for (int c = 0; c < 4; ++c) gp[c] += valid ? sfr[s][c] : 0.f;
    }
    #pragma unroll
    for (int c = 0; c < 4; ++c) gp[c] = wave_red(gp[c]);
    if (lane == 0) gredv[wid] = make_float4(gp[0], gp[1], gp[2], gp[3]);
    __syncthreads();                        // also orders X staging

    const float4 gv = f4add(f4add(gredv[0], gredv[1]), f4add(gredv[2], gredv[3]));
    float g[4];
    g[0] = fmaxf(gv.x * INVFN, EPSV);  g[1] = fmaxf(gv.y * INVFN, EPSV);
    g[2] = fmaxf(gv.z * INVFN, EPSV);  g[3] = fmaxf(gv.w * INVFN, EPSV);
    #pragma unroll
    for (int c = 0; c < 4; ++c) {
      invgs[c] = fast_rsq(g[c]);            // sqrt(g) >= sqrt(1e-3) > EPS
      // w = g / max(2*sqrt(s), 1e-5)  ==  g * min(0.5*rsqrt(s), 1e5)
      #pragma unroll
      for (int s = 0; s < 4; ++s) {
        const bool valid = (nb + 64*s) < NFR;
        w[s][c] = valid ? g[c] * fminf(0.5f * fast_rsq(sfr[s][c]), 1e5f) : 0.f;
      }
    }
  }

  // ---- load Y, normalize ----
  float yre[4][4], yim[4][4];
  #pragma unroll
  for (int s = 0; s < 4; ++s) {
    const int na = min(nb + 64*s, 999);
    #pragma unroll
    for (int c = 0; c < 4; ++c) {
      yre[s][c] = Y[base + (size_t)c*CSTRIDE + na] * invgs[c];
      yim[s][c] = Y[base + (size_t)c*CSTRIDE + na + PLANE] * invgs[c];
    }
  }

  int par = 0;
  float p[12], vr_[4], vi_[4];

  // ----- 4 source stages -----
  #pragma unroll
  for (int src = 0; src < 4; ++src) {
    #pragma unroll
    for (int j = 0; j < 12; ++j) p[j] = 0.f;
    #pragma unroll
    for (int s = 0; s < 4; ++s) {
      const float zr = yre[s][src], zi = yim[s][src];
      const float zz = zr*zr + zi*zi;
      #pragma unroll
      for (int c = 0; c < 4; ++c) {
        const float wk = w[s][c];
        p[8+c] = fmaf(wk, zz, p[8+c]);
        if (c != src) {                      // p[src], p[4+src] are dead
          p[c]   = fmaf(wk, yre[s][c]*zr + yim[s][c]*zi, p[c]);
          p[4+c] = fmaf(wk, yim[s][c]*zr - yre[s][c]*zi, p[4+c]);
        }
      }
    }
    #pragma unroll
    for (int j = 0; j < 12; ++j)
      if (j != src && j != 4 + src) p[j] = wave_red(p[j]);
    if (lane == 0) {
      redv[par][wid][0] = make_float4(p[0], p[1], p[2],  p[3]);
      redv[par][wid][1] = make_float4(p[4], p[5], p[6],  p[7]);
      redv[par][wid][2] = make_float4(p[8], p[9], p[10], p[11]);
    }
    __syncthreads();
    {
      const float4 s0 = f4add(f4add(redv[par][0][0], redv[par][1][0]),
                              f4add(redv[par][2][0], redv[par][3][0]));
      const float4 s1 = f4add(f4add(redv[par][0][1], redv[par][1][1]),
                              f4add(redv[par][2][1], redv[par][3][1]));
      const float4 s2 = f4add(f4add(redv[par][0][2], redv[par][1][2]),
                              f4add(redv[par][2][2], redv[par][3][2]));
      p[0]=s0.x; p[1]=s0.y; p[2]=s0.z;  p[3]=s0.w;
      p[4]=s1.x; p[5]=s1.y; p[6]=s1.z;  p[7]=s1.w;
      p[8]=s2.x; p[9]=s2.y; p[10]=s2.z; p[11]=s2.w;
    }
    par ^= 1;

    float vd[4];
    #pragma unroll
    for (int c = 0; c < 4; ++c) vd[c] = fmaxf(p[8+c] * INVNF, EPSV);
    #pragma unroll
    for (int c = 0; c < 4; ++c) {
      const float inv = INVNF * fast_rcp(vd[c]);
      vr_[c] = p[c] * inv;  vi_[c] = p[4+c] * inv;
    }
    vr_[src] = 1.0f - fast_rsq(vd[src]);  vi_[src] = 0.0f;

    #pragma unroll
    for (int s = 0; s < 4; ++s) {
      const float zr = yre[s][src], zi = yim[s][src];
      #pragma unroll
      for (int c = 0; c < 4; ++c) {
        yre[s][c] -= vr_[c]*zr - vi_[c]*zi;
        yim[s][c] -= vr_[c]*zi + vi_[c]*zr;
      }
    }
  }

  // ----- 20 dereverb stages via per-src register tap-window -----
  // xw[s][o] = X[src][nb + 64*s - 6 + o], o=0..4; tap t reads xw[s][t].
  for (int src = 0; src < 4; ++src) {
    const float* px = xre[src];
    const float* py = xim[src];
    float xwr[4][5], xwi[4][5];
    #pragma unroll
    for (int s = 0; s < 4; ++s) {
      #pragma unroll
      for (int o = 0; o < 5; ++o) {
        const int m = nb + 64*s - 6 + o;
        int mc = m;
        if (s == 0) mc = max(m, 0);         // m<0 only possible in slot 0 (wave 0)
        if (s == 3) mc = min(m, 999);       // m>999 only possible in slot 3 (wave 3)
        float vr = px[mc], vi = py[mc];
        if (s == 0) {                        // zero the pre-signal taps
          vr = (m >= 0) ? vr : 0.f;
          vi = (m >= 0) ? vi : 0.f;
        }
        xwr[s][o] = vr; xwi[s][o] = vi;      // n>=NFR slots masked by w=0
      }
    }

    #pragma unroll
    for (int tap = 0; tap < 5; ++tap) {
      #pragma unroll
      for (int j = 0; j < 12; ++j) p[j] = 0.f;
      #pragma unroll
      for (int s = 0; s < 4; ++s) {
        const float zr = xwr[s][tap], zi = xwi[s][tap];
        const float zz = zr*zr + zi*zi;
        #pragma unroll
        for (int c = 0; c < 4; ++c) {
          const float wk = w[s][c];
          p[8+c] = fmaf(wk, zz, p[8+c]);
          p[c]   = fmaf(wk, yre[s][c]*zr + yim[s][c]*zi, p[c]);
          p[4+c] = fmaf(wk, yim[s][c]*zr - yre[s][c]*zi, p[4+c]);
        }
      }
      #pragma unroll
      for (int j = 0; j < 12; ++j) p[j] = wave_red(p[j]);
      if (lane == 0) {
        redv[par][wid][0] = make_float4(p[0], p[1], p[2],  p[3]);
        redv[par][wid][1] = make_float4(p[4], p[5], p[6],  p[7]);
        redv[par][wid][2] = make_float4(p[8], p[9], p[10], p[11]);
      }
      __syncthreads();
      {
        const float4 s0 = f4add(f4add(redv[par][0][0], redv[par][1][0]),
                                f4add(redv[par][2][0], redv[par][3][0]));
        const float4 s1 = f4add(f4add(redv[par][0][1], redv[par][1][1]),
                                f4add(redv[par][2][1], redv[par][3][1]));
        const float4 s2 = f4add(f4add(redv[par][0][2], redv[par][1][2]),
                                f4add(redv[par][2][2], redv[par][3][2]));
        p[0]=s0.x; p[1]=s0.y; p[2]=s0.z;  p[3]=s0.w;
        p[4]=s1.x; p[5]=s1.y; p[6]=s1.z;  p[7]=s1.w;
        p[8]=s2.x; p[9]=s2.y; p[10]=s2.z; p[11]=s2.w;
      }
      par ^= 1;

      #pragma unroll
      for (int c = 0; c < 4; ++c) {          // dereverb: no inv_nf (matches ref)
        const float inv = fast_rcp(fmaxf(p[8+c], EPSV));
        vr_[c] = p[c] * inv;  vi_[c] = p[4+c] * inv;
      }
      #pragma unroll
      for (int s = 0; s < 4; ++s) {
        const float zr = xwr[s][tap], zi = xwi[s][tap];
        #pragma unroll
        for (int c = 0; c < 4; ++c) {
          yre[s][c] -= vr_[c]*zr - vi_[c]*zi;
          yim[s][c] -= vr_[c]*zi + vi_[c]*zr;
        }
      }
    }
  }

  // ---- write back Y (+ optional |Y|^2 plane; same indexing as Y) ----
  #pragma unroll
  for (int s = 0; s < 4; ++s) {
    const int n = nb + 64*s;
    if (n < NFR) {
      #pragma unroll
      for (int c = 0; c < 4; ++c) {
        const float yr = yre[s][c], yi = yim[s][c];
        Y[base + (size_t)c*CSTRIDE + n]         = yr;
        Y[base + (size_t)c*CSTRIDE + n + PLANE] = yi;
        if (mag) mag[base + (size_t)c*CSTRIDE + n] = yr*yr + yi*yi;
      }
    }
  }
}

extern "C" void kernel_launch(void* const* d_in, const int* in_sizes, int n_in,
                              void* d_out, int out_size, void* d_ws, size_t ws_size,
                              hipStream_t stream)
{
  const float* Xr = (const float*)d_in[0];
  const float* Xi = (const float*)d_in[1];
  float* Y = (float*)d_out;                 // Yr | Yi, final layout

  const bool big_ws = ws_size >= (size_t)(4096000 + 128000 + 8000) * 4;
  if (big_ws) {
    float* mag   = (float*)d_ws;            // 4,096,000 floats
    float* part2 = mag + 4096000;           // 128,000
    float* sumf  = part2 + 128000;          // 8,000
    init_y<<<1024, 256, 0, stream>>>(Xr, Xi, Y, mag);
    for (int it = 0; it < NIT; ++it) {
      partial_mag<<<128, 256, 0, stream>>>(mag, part2);
      finish_mag<<<8, 256, 0, stream>>>(part2, sumf);
      // last iteration: nobody consumes mag afterwards -> skip the extra write
      iter_c<<<1024, 256, 0, stream>>>(Xr, Xi, Y, sumf,
                                       (it < NIT - 1) ? mag : nullptr);
    }
  } else {
    float* part = (float*)d_ws;             // 256,000 floats
    float* sumf = part + 256000;            // 8,000
    init_y<<<1024, 256, 0, stream>>>(Xr, Xi, Y, nullptr);
    for (int it = 0; it < NIT; ++it) {
      partial_sumf<<<256, 256, 0, stream>>>(Y, part);
      finish_sumf<<<32, 256, 0, stream>>>(part, sumf);
      iter_c<<<1024, 256, 0, stream>>>(Xr, Xi, Y, sumf, nullptr);
    }
  }
}

// Round 10
// 305.164 us; speedup vs baseline: 1.4752x; 1.4752x over previous
//
#include <hip/hip_runtime.h>

// OverISS-T  (input (2,4,512,1000) complex, 5 iterations)
// Multi-kernel, stream-ordered. Y state lives in d_out (Yr | Yi planes, final
// output layout). W/H are dead state w.r.t. Y — skipped.
//
// Round 10 (base = R8 2-wave structure; R9's 4-wave reverted — tail overhead
// duplication): packed dual-FP32 (v_pk_fma_f32 / v_pk_mul_f32) for the
// complex accumulate (y·conj(z)), the rank-1 update, and weight application.
// X staged INTERLEAVED ⟨re,im⟩ in LDS so tap windows load as ds_read_b64
// straight into packed register pairs.

constexpr int NCH = 4;
constexpr int NFQ = 512;
constexpr int NFR = 1000;
constexpr int NIT = 5;
constexpr float EPSV  = 1e-3f;
constexpr float INVNF = 1.0f / 1000.0f;
constexpr float INVFN = 1.0f / (512.0f * 1000.0f);
constexpr size_t PLANE = 4096000;             // 2*4*512*1000
constexpr size_t CSTRIDE = (size_t)NFQ * NFR; // 512000

typedef float f2 __attribute__((ext_vector_type(2)));

__device__ __forceinline__ float fast_rcp(float x) { return __builtin_amdgcn_rcpf(x); }
__device__ __forceinline__ float fast_rsq(float x) { return __builtin_amdgcn_rsqf(x); }

template <int CTRL>
__device__ __forceinline__ float dpp_add(float x) {
  return x + __int_as_float(__builtin_amdgcn_update_dpp(
      0, __float_as_int(x), CTRL, 0xF, 0xF, true));
}
__device__ __forceinline__ float wave_red(float x) {
  x = dpp_add<0xB1>(x);    // quad_perm [1,0,3,2]
  x = dpp_add<0x4E>(x);    // quad_perm [2,3,0,1]
  x = dpp_add<0x141>(x);   // row_half_mirror
  x = dpp_add<0x140>(x);   // row_mirror
  x = dpp_add<0x142>(x);   // row_bcast15
  x = dpp_add<0x143>(x);   // row_bcast31
  return __int_as_float(__builtin_amdgcn_readlane(__float_as_int(x), 63));
}

// u = y * conj(z):  u.lo = yr*zr + yi*zi ; u.hi = yi*zr - yr*zi   (2 VOP3P)
__device__ __forceinline__ f2 cmulconj(f2 y, f2 z) {
  f2 t, u;
  asm("v_pk_mul_f32 %0, %1, %2 op_sel:[1,1] op_sel_hi:[0,1] neg_hi:[1,0]"
      : "=v"(t) : "v"(y), "v"(z));
  // t.lo = yi*zi ; t.hi = -yr*zi
  asm("v_pk_fma_f32 %0, %1, %2, %3 op_sel_hi:[1,0,1]"
      : "=v"(u) : "v"(y), "v"(z), "v"(t));
  // u.lo = yr*zr + t.lo ; u.hi = yi*zr + t.hi
  return u;
}
// p += w * u   (w broadcast from lo lane)
__device__ __forceinline__ void pk_acc(f2& p, f2 w2, f2 u) {
  asm("v_pk_fma_f32 %0, %1, %2, %0 op_sel_hi:[0,1,1]"
      : "+v"(p) : "v"(w2), "v"(u));
}
// y -= v*z (complex):  y.lo -= vr*zr - vi*zi ; y.hi -= vr*zi + vi*zr
__device__ __forceinline__ void cupdate(f2& y, f2 v, f2 z) {
  asm("v_pk_fma_f32 %0, %1, %2, %0 op_sel_hi:[0,1,1] neg_lo:[1,0,0] neg_hi:[1,0,0]"
      : "+v"(y) : "v"(v), "v"(z));   // y += (-vr)*⟨zr,zi⟩
  asm("v_pk_fma_f32 %0, %1, %2, %0 op_sel:[1,1,0] op_sel_hi:[1,0,1] neg_hi:[1,0,0]"
      : "+v"(y) : "v"(v), "v"(z));   // y.lo += vi*zi ; y.hi += -vi*zr
}

// ---- Y0 = 0.999*X[c] + 0.001*sum_d X[d];  optional |Y0|^2 plane ----
__global__ __launch_bounds__(256, 4)
void init_y(const float* __restrict__ Xr, const float* __restrict__ Xi,
            float* __restrict__ Y, float* __restrict__ mag)
{
  const int bf = blockIdx.x, b = bf >> 9, f = bf & 511;
  const size_t base = ((size_t)b * NCH * NFQ + f) * NFR;
  const int tid = threadIdx.x;
  if (tid < 250) {
    const int nq = 4 * tid;
    float4 xr[4], xi[4];
    #pragma unroll
    for (int c = 0; c < 4; ++c) {
      xr[c] = *(const float4*)(Xr + base + (size_t)c * CSTRIDE + nq);
      xi[c] = *(const float4*)(Xi + base + (size_t)c * CSTRIDE + nq);
    }
    float4 sr, si;
    sr.x = xr[0].x+xr[1].x+xr[2].x+xr[3].x;  si.x = xi[0].x+xi[1].x+xi[2].x+xi[3].x;
    sr.y = xr[0].y+xr[1].y+xr[2].y+xr[3].y;  si.y = xi[0].y+xi[1].y+xi[2].y+xi[3].y;
    sr.z = xr[0].z+xr[1].z+xr[2].z+xr[3].z;  si.z = xi[0].z+xi[1].z+xi[2].z+xi[3].z;
    sr.w = xr[0].w+xr[1].w+xr[2].w+xr[3].w;  si.w = xi[0].w+xi[1].w+xi[2].w+xi[3].w;
    #pragma unroll
    for (int c = 0; c < 4; ++c) {
      float4 yr, yi;
      yr.x = 0.999f*xr[c].x + 0.001f*sr.x;  yi.x = 0.999f*xi[c].x + 0.001f*si.x;
      yr.y = 0.999f*xr[c].y + 0.001f*sr.y;  yi.y = 0.999f*xi[c].y + 0.001f*si.y;
      yr.z = 0.999f*xr[c].z + 0.001f*sr.z;  yi.z = 0.999f*xi[c].z + 0.001f*si.z;
      yr.w = 0.999f*xr[c].w + 0.001f*sr.w;  yi.w = 0.999f*xi[c].w + 0.001f*si.w;
      *(float4*)(Y + base + (size_t)c * CSTRIDE + nq)         = yr;
      *(float4*)(Y + base + (size_t)c * CSTRIDE + nq + PLANE) = yi;
      if (mag) {
        float4 m;
        m.x = yr.x*yr.x + yi.x*yi.x;  m.y = yr.y*yr.y + yi.y*yi.y;
        m.z = yr.z*yr.z + yi.z*yi.z;  m.w = yr.w*yr.w + yi.w*yi.w;
        *(float4*)(mag + base + (size_t)c * CSTRIDE + nq) = m;
      }
    }
  }
}

// ---- mag reduction over f, stage 1: 32-f chunks (128 blocks) ----
__global__ __launch_bounds__(256, 4)
void partial_mag(const float* __restrict__ mag, float* __restrict__ part2)
{
  const int id = blockIdx.x;                  // b | c | k
  const int k = id & 15, c = (id >> 4) & 3, b = id >> 6;
  const int tid = threadIdx.x;
  if (tid < 250) {
    const int nq = 4 * tid;
    const float* base = mag + ((size_t)((b*4+c)*NFQ + k*32)) * NFR + nq;
    float4 acc = make_float4(0.f, 0.f, 0.f, 0.f);
    for (int ff = 0; ff < 32; ++ff) {
      const float4 v = *(const float4*)(base + (size_t)ff * NFR);
      acc.x += v.x; acc.y += v.y; acc.z += v.z; acc.w += v.w;
    }
    *(float4*)(part2 + ((size_t)((b*4+c)*16 + k)) * NFR + nq) = acc;
  }
}

// ---- mag reduction stage 2 ----
__global__ __launch_bounds__(256, 4)
void finish_mag(const float* __restrict__ part2, float* __restrict__ sumf)
{
  const int t = blockIdx.x * 256 + threadIdx.x;   // 8 blocks, 2000 quads
  if (t < 2000) {
    const int b = t / 1000, r = t - 1000 * b;
    const int c = r / 250,  qn = r - 250 * c;
    const float* base = part2 + ((size_t)((b*4+c)*16)) * NFR + 4*qn;
    float4 acc = make_float4(0.f, 0.f, 0.f, 0.f);
    #pragma unroll
    for (int k = 0; k < 16; ++k) {
      const float4 v = *(const float4*)(base + (size_t)k * NFR);
      acc.x += v.x; acc.y += v.y; acc.z += v.z; acc.w += v.w;
    }
    *(float4*)(sumf + (size_t)b*4000 + c*1000 + 4*qn) = acc;
  }
}

// ---- legacy sumf path (reads Y) — fallback when ws is small ----
__global__ __launch_bounds__(256, 4)
void partial_sumf(const float* __restrict__ Y, float* __restrict__ part)
{
  const int id = blockIdx.x;                 // b | c | q
  const int q = id & 31, c = (id >> 5) & 3, b = id >> 7;
  const size_t base = (size_t)(b * NCH + c) * CSTRIDE + (size_t)q * 16 * NFR;
  float acc[4] = {0.f, 0.f, 0.f, 0.f};
  for (int ff = 0; ff < 16; ++ff) {
    #pragma unroll
    for (int k = 0; k < 4; ++k) {
      const int n = threadIdx.x + 256 * k;
      if (n < NFR) {
        const float r = Y[base + (size_t)ff * NFR + n];
        const float i = Y[base + (size_t)ff * NFR + n + PLANE];
        acc[k] = fmaf(r, r, acc[k]);
        acc[k] = fmaf(i, i, acc[k]);
      }
    }
  }
  #pragma unroll
  for (int k = 0; k < 4; ++k) {
    const int n = threadIdx.x + 256 * k;
    if (n < NFR) part[((size_t)(b * NCH + c) * 32 + q) * NFR + n] = acc[k];
  }
}
__global__ __launch_bounds__(256, 4)
void finish_sumf(const float* __restrict__ part, float* __restrict__ sumf)
{
  const int o = blockIdx.x * 256 + threadIdx.x;
  if (o < 8000) {
    const int b = o / 4000;
    const int rem = o - b * 4000;
    const int c = rem / 1000;
    const int n = rem - c * 1000;
    const float* p = part + ((size_t)(b * NCH + c) * 32) * NFR + n;
    float s = 0.f;
    for (int q = 0; q < 32; ++q) s += p[(size_t)q * NFR];
    sumf[o] = s;
  }
}

// ---- stage C: one full iteration for one (b,f) slice — TWO waves, packed ----
// wave wid owns slots s=0..7: frame n = 512*wid + 64*s + lane
__global__ __launch_bounds__(128, 2)
void iter_c(const float* __restrict__ Xr, const float* __restrict__ Xi,
            float* __restrict__ Y, const float* __restrict__ sumf,
            float* __restrict__ mag)
{
  __shared__ f2 x2[NCH][NFR];        // interleaved ⟨re,im⟩, 32 KB
  __shared__ float red[2][2][12];    // [parity][wave][12]
  __shared__ float gred[2][4];

  const int tid  = threadIdx.x;
  const int lane = tid & 63;
  const int wid  = tid >> 6;
  const int ow   = wid ^ 1;
  const int bf   = blockIdx.x, b = bf >> 9, f = bf & 511;
  const size_t base = ((size_t)b * NCH * NFQ + f) * NFR;
  const int nb = 512 * wid + lane;          // frame of slot 0

  // ---- stage X into LDS interleaved (2 b128 writes per 4 frames) ----
  for (int j = tid; j < NCH * 250; j += 128) {
    const int c = j / 250, q = j - c * 250;
    const float4 vr = *(const float4*)(Xr + base + (size_t)c*CSTRIDE + 4*q);
    const float4 vi = *(const float4*)(Xi + base + (size_t)c*CSTRIDE + 4*q);
    *(float4*)(&x2[c][4*q])     = make_float4(vr.x, vi.x, vr.y, vi.y);
    *(float4*)(&x2[c][4*q + 2]) = make_float4(vr.z, vi.z, vr.w, vi.w);
  }

  // ---- sumf -> g (cross-wave via gred), invgs, weights w ----
  float w[8][4], invgs[4];
  {
    float sfr[8][4];
    const float* sfb = sumf + b * 4000;
    #pragma unroll
    for (int s = 0; s < 8; ++s) {
      const int na = min(nb + 64*s, 999);
      #pragma unroll
      for (int c = 0; c < 4; ++c) sfr[s][c] = sfb[c*1000 + na];
    }
    float gp[4] = {0.f, 0.f, 0.f, 0.f};
    #pragma unroll
    for (int s = 0; s < 8; ++s) {
      const bool valid = (nb + 64*s) < NFR;
      #pragma unroll
      for (int c = 0; c < 4; ++c) gp[c] += valid ? sfr[s][c] : 0.f;
    }
    #pragma unroll
    for (int c = 0; c < 4; ++c) gp[c] = wave_red(gp[c]);
    if (lane == 0) {
      #pragma unroll
      for (int c = 0; c < 4; ++c) gred[wid][c] = gp[c];
    }
    __syncthreads();                        // also orders X staging

    #pragma unroll
    for (int c = 0; c < 4; ++c) {
      const float g = fmaxf((gred[0][c] + gred[1][c]) * INVFN, EPSV);
      invgs[c] = fast_rsq(g);               // sqrt(g) >= sqrt(1e-3) > EPS
      #pragma unroll
      for (int s = 0; s < 8; ++s) {
        const bool valid = (nb + 64*s) < NFR;
        w[s][c] = valid ? g * fminf(0.5f * fast_rsq(sfr[s][c]), 1e5f) : 0.f;
      }
    }
  }

  // ---- load Y packed, normalize ----
  f2 y2[8][4];
  #pragma unroll
  for (int s = 0; s < 8; ++s) {
    const int na = min(nb + 64*s, 999);
    #pragma unroll
    for (int c = 0; c < 4; ++c) {
      f2 t;
      t.x = Y[base + (size_t)c*CSTRIDE + na] * invgs[c];
      t.y = Y[base + (size_t)c*CSTRIDE + na + PLANE] * invgs[c];
      y2[s][c] = t;
    }
  }

  int par = 0;
  f2 p2[4]; float pd[4], vr_[4], vi_[4];

  // ----- 4 source stages -----
  #pragma unroll
  for (int src = 0; src < 4; ++src) {
    #pragma unroll
    for (int c = 0; c < 4; ++c) { p2[c] = (f2){0.f, 0.f}; pd[c] = 0.f; }
    #pragma unroll
    for (int s = 0; s < 8; ++s) {
      const f2 z = y2[s][src];
      const float zz = z.x*z.x + z.y*z.y;
      #pragma unroll
      for (int c = 0; c < 4; ++c) {
        const float wk = w[s][c];
        pd[c] = fmaf(wk, zz, pd[c]);
        if (c != src) {
          const f2 u = cmulconj(y2[s][c], z);
          f2 w2; w2.x = wk; w2.y = wk;
          pk_acc(p2[c], w2, u);
        }
      }
    }
    #pragma unroll
    for (int c = 0; c < 4; ++c) {
      pd[c] = wave_red(pd[c]);
      if (c != src) { p2[c].x = wave_red(p2[c].x); p2[c].y = wave_red(p2[c].y); }
    }
    if (lane == 0) {
      #pragma unroll
      for (int c = 0; c < 4; ++c) {
        red[par][wid][c]     = p2[c].x;
        red[par][wid][4 + c] = p2[c].y;
        red[par][wid][8 + c] = pd[c];
      }
    }
    __syncthreads();
    #pragma unroll
    for (int c = 0; c < 4; ++c) {
      p2[c].x += red[par][ow][c];
      p2[c].y += red[par][ow][4 + c];
      pd[c]   += red[par][ow][8 + c];
    }
    par ^= 1;

    f2 vp[4];
    #pragma unroll
    for (int c = 0; c < 4; ++c) {
      const float vd  = fmaxf(pd[c] * INVNF, EPSV);
      const float inv = INVNF * fast_rcp(vd);
      vr_[c] = p2[c].x * inv;  vi_[c] = p2[c].y * inv;
    }
    vr_[src] = 1.0f - fast_rsq(fmaxf(pd[src] * INVNF, EPSV));
    vi_[src] = 0.0f;
    #pragma unroll
    for (int c = 0; c < 4; ++c) { vp[c].x = vr_[c]; vp[c].y = vi_[c]; }

    #pragma unroll
    for (int s = 0; s < 8; ++s) {
      const f2 z = y2[s][src];            // copy before in-place updates
      #pragma unroll
      for (int c = 0; c < 4; ++c) cupdate(y2[s][c], vp[c], z);
    }
  }

  // ----- 20 dereverb stages via packed per-src register tap-window -----
  // xw[s][o] = X[src][nb + 64*s - 6 + o], o=0..4; tap t reads xw[s][t].
  for (int src = 0; src < 4; ++src) {
    f2 xw[8][5];
    #pragma unroll
    for (int s = 0; s < 8; ++s) {
      #pragma unroll
      for (int o = 0; o < 5; ++o) {
        const int m = nb + 64*s - 6 + o;
        int mc = m;
        if (s == 0) mc = max(m, 0);       // m<0 only possible in slot 0 (wave 0)
        if (s == 7) mc = min(m, 999);     // m>999 only possible in slot 7 (wave 1)
        f2 v = x2[src][mc];
        if (s == 0 && m < 0) v = (f2){0.f, 0.f};   // pre-signal taps are zero
        xw[s][o] = v;                      // n>=NFR slots masked by w=0
      }
    }

    #pragma unroll
    for (int tap = 0; tap < 5; ++tap) {
      #pragma unroll
      for (int c = 0; c < 4; ++c) { p2[c] = (f2){0.f, 0.f}; pd[c] = 0.f; }
      #pragma unroll
      for (int s = 0; s < 8; ++s) {
        const f2 z = xw[s][tap];
        const float zz = z.x*z.x + z.y*z.y;
        #pragma unroll
        for (int c = 0; c < 4; ++c) {
          const float wk = w[s][c];
          pd[c] = fmaf(wk, zz, pd[c]);
          const f2 u = cmulconj(y2[s][c], z);
          f2 w2; w2.x = wk; w2.y = wk;
          pk_acc(p2[c], w2, u);
        }
      }
      #pragma unroll
      for (int c = 0; c < 4; ++c) {
        p2[c].x = wave_red(p2[c].x);
        p2[c].y = wave_red(p2[c].y);
        pd[c]   = wave_red(pd[c]);
      }
      if (lane == 0) {
        #pragma unroll
        for (int c = 0; c < 4; ++c) {
          red[par][wid][c]     = p2[c].x;
          red[par][wid][4 + c] = p2[c].y;
          red[par][wid][8 + c] = pd[c];
        }
      }
      __syncthreads();
      #pragma unroll
      for (int c = 0; c < 4; ++c) {
        p2[c].x += red[par][ow][c];
        p2[c].y += red[par][ow][4 + c];
        pd[c]   += red[par][ow][8 + c];
      }
      par ^= 1;

      f2 vp[4];
      #pragma unroll
      for (int c = 0; c < 4; ++c) {        // dereverb: no inv_nf (matches ref)
        const float inv = fast_rcp(fmaxf(pd[c], EPSV));
        vp[c].x = p2[c].x * inv;  vp[c].y = p2[c].y * inv;
      }
      #pragma unroll
      for (int s = 0; s < 8; ++s) {
        const f2 z = xw[s][tap];
        #pragma unroll
        for (int c = 0; c < 4; ++c) cupdate(y2[s][c], vp[c], z);
      }
    }
  }

  // ---- write back Y (+ optional |Y|^2 plane) ----
  #pragma unroll
  for (int s = 0; s < 8; ++s) {
    const int n = nb + 64*s;
    if (n < NFR) {
      #pragma unroll
      for (int c = 0; c < 4; ++c) {
        const float yr = y2[s][c].x, yi = y2[s][c].y;
        Y[base + (size_t)c*CSTRIDE + n]         = yr;
        Y[base + (size_t)c*CSTRIDE + n + PLANE] = yi;
        if (mag) mag[base + (size_t)c*CSTRIDE + n] = yr*yr + yi*yi;
      }
    }
  }
}

extern "C" void kernel_launch(void* const* d_in, const int* in_sizes, int n_in,
                              void* d_out, int out_size, void* d_ws, size_t ws_size,
                              hipStream_t stream)
{
  const float* Xr = (const float*)d_in[0];
  const float* Xi = (const float*)d_in[1];
  float* Y = (float*)d_out;                 // Yr | Yi, final layout

  const bool big_ws = ws_size >= (size_t)(4096000 + 128000 + 8000) * 4;
  if (big_ws) {
    float* mag   = (float*)d_ws;            // 4,096,000 floats
    float* part2 = mag + 4096000;           // 128,000
    float* sumf  = part2 + 128000;          // 8,000
    init_y<<<1024, 256, 0, stream>>>(Xr, Xi, Y, mag);
    for (int it = 0; it < NIT; ++it) {
      partial_mag<<<128, 256, 0, stream>>>(mag, part2);
      finish_mag<<<8, 256, 0, stream>>>(part2, sumf);
      iter_c<<<1024, 128, 0, stream>>>(Xr, Xi, Y, sumf,
                                       (it < NIT - 1) ? mag : nullptr);
    }
  } else {
    float* part = (float*)d_ws;             // 256,000 floats
    float* sumf = part + 256000;            // 8,000
    init_y<<<1024, 256, 0, stream>>>(Xr, Xi, Y, nullptr);
    for (int it = 0; it < NIT; ++it) {
      partial_sumf<<<256, 256, 0, stream>>>(Y, part);
      finish_sumf<<<32, 256, 0, stream>>>(part, sumf);
      iter_c<<<1024, 128, 0, stream>>>(Xr, Xi, Y, sumf, nullptr);
    }
  }
}